// Round 8
// baseline (161.671 us; speedup 1.0000x reference)
//
#include <hip/hip_runtime.h>

// All-pairs edge MLP, N_E=1024, NIN=64, HID=128, OUT=64, fp32.
// out[i] = ((1/1023) * sum_{k!=i} tanh(A[i]+B[k])) @ W2 + b2
//   A = x@W1[:64,:],  B = x@W1[64:,:] + b1
// Rank-separated tanh via 2D Chebyshev (P=30, domain [-5.5,5.5]^2):
//   sum_k tanh(a_i+b_k) = sum_p T_p(a_i) V_p[h],  V = C @ M,
//   M_q[h] = sum_k T_q(b_k[h]).
//
// R12: 3 wide kernels, kernel-boundary sync only, no global atomics, no
// memset, no register hoists. R11's prep8 failure was diagnosed from
// counters: FETCH_SIZE=438MB (scratch spill storm from the 128-float W1
// hoist) + 9-block grid + 32 serial rows/thread -> 52.7us @ VALUBusy 1%.
//  - prep32: 32 blocks x 1024 thr, 32 rows/block, 4 rows/thread, W1
//    re-read via L1 (no hoist). Moments reduced block-locally (LDS
//    atomics) -> private copy M32[b], plain stores (no zeroed memory).
//  - v_kernel: 30 blocks x 256 thr. Block p builds the C dependencies in
//    its own LDS (input-independent DCT-I), sums the 32 moment copies
//    (coalesced, L2-resident), writes V[p][:]. V computed once, not per
//    combine block (R1 regression removed).
//  - combine: 256 x 512. Stages V (15KB), Chebyshev eval + exact self
//    term, fused S@W2 + b2.
// Graph: prep32 -> v_kernel -> combine. 3 nodes.

#define N_E  1024
#define NIN  64
#define HID  128
#define OUTD 64
#define PCH  30      // Chebyshev terms per variable
#define NQ   32      // DCT-I grid: NQ+1 Lobatto points
#define S_CH 5.5f
#define NCPY 32      // private moment copies (= # prep blocks)
#define RPB  (N_E / NCPY)   // 32 rows per prep block

static constexpr float INV_S     = 1.0f / 5.5f;
static constexpr float TWO_LOG2E = 2.8853900817779268f; // 2*log2(e)
static constexpr float PI_F      = 3.14159265358979323846f;

__device__ __forceinline__ float tanh_fast(float u) {
  // tanh(u) = 1 - 2/(1+exp2(u*2log2e))
  return 1.0f - 2.0f * __builtin_amdgcn_rcpf(
      1.0f + __builtin_amdgcn_exp2f(u * TWO_LOG2E));
}

// ---- K1: 32 blocks x 1024. Each block: A,B for its 32 rows + block-local
// Chebyshev moments -> private copy M32[b] (plain stores).
__global__ __launch_bounds__(1024) void prep32_kernel(
    const float* __restrict__ x, const float* __restrict__ W1,
    const float* __restrict__ b1,
    float* __restrict__ A, float* __restrict__ B,
    float* __restrict__ M32) {
  __shared__ float xs[RPB][NIN];        // 8 KB
  __shared__ float Msub[PCH * HID];     // 15 KB
  const int t = threadIdx.x;
  const int b = blockIdx.x;
  const int r0 = b * RPB;
  for (int idx = t; idx < RPB * NIN; idx += 1024)
    ((float*)xs)[idx] = x[r0 * NIN + idx];
  for (int idx = t; idx < PCH * HID; idx += 1024) Msub[idx] = 0.f;
  __syncthreads();

  const int h = t & (HID - 1), sub = t >> 7;    // 8 subs x 4 rows each
  const float bb = b1[h];
  float macc[PCH];
  #pragma unroll
  for (int q = 0; q < PCH; ++q) macc[q] = 0.f;

  #pragma unroll
  for (int j = 0; j < 4; ++j) {                 // 4 rows per thread
    const int r = sub * 4 + j;
    float aA = 0.f, aB = 0.f;
    #pragma unroll 8
    for (int f = 0; f < NIN; ++f) {
      const float xv = xs[r][f];                // wave-broadcast
      aA += xv * W1[f * HID + h];               // coalesced over h, L1-hot
      aB += xv * W1[(NIN + f) * HID + h];
    }
    aB += bb;
    A[(r0 + r) * HID + h] = aA;                 // coalesced over h
    B[(r0 + r) * HID + h] = aB;
    const float c = fminf(fmaxf(aB, -S_CH), S_CH) * INV_S;
    float m0 = 1.f, m1 = c;
    macc[0] += 1.f; macc[1] += c;
    const float c2x = c + c;
    #pragma unroll
    for (int q = 2; q < PCH; ++q) {
      const float m2 = c2x * m1 - m0;
      macc[q] += m2;
      m0 = m1; m1 = m2;
    }
  }
  // block-local reduction: 8 subs per (q,h), LDS atomics
  #pragma unroll
  for (int q = 0; q < PCH; ++q) atomicAdd(&Msub[q * HID + h], macc[q]);
  __syncthreads();
  for (int idx = t; idx < PCH * HID; idx += 1024)
    M32[b * (PCH * HID) + idx] = Msub[idx];     // private copy, plain stores
}

// ---- K2: 30 blocks (p) x 256. Build C deps in LDS, sum 32 moment copies,
// write V[p][h] = sum_q C[p][q] * Ms[q][h].
__global__ __launch_bounds__(256) void v_kernel(
    const float* __restrict__ M32, float* __restrict__ V) {
  __shared__ float ctab[NQ + 1];
  __shared__ float fg[(NQ + 1) * (NQ + 2)];   // 4.5 KB
  __shared__ float G[PCH * (NQ + 2)];         // 4.1 KB
  __shared__ float Crow[PCH];
  __shared__ float Ms[PCH * HID];             // 15 KB
  const int t = threadIdx.x;
  const int p = blockIdx.x;

  if (t <= NQ) ctab[t] = cosf((float)t * (PI_F / (float)NQ));
  __syncthreads();
  for (int idx = t; idx < (NQ + 1) * (NQ + 1); idx += 256) {
    const int j = idx / (NQ + 1), l = idx % (NQ + 1);
    fg[j * (NQ + 2) + l] = tanh_fast(S_CH * (ctab[j] + ctab[l]));
  }
  __syncthreads();
  for (int idx = t; idx < PCH * (NQ + 1); idx += 256) {
    const int q = idx / (NQ + 1), j = idx % (NQ + 1);
    const float cphi = ctab[q];
    float c0 = 1.f, c1 = cphi;
    float s = 0.5f * fg[j * (NQ + 2) + 0];     // l=0: w=1/2, cos=1
    for (int l = 1; l <= NQ; ++l) {
      const float w = (l == NQ) ? 0.5f : 1.0f;
      s += w * fg[j * (NQ + 2) + l] * c1;
      const float c2 = 2.f * cphi * c1 - c0; c0 = c1; c1 = c2;
    }
    G[q * (NQ + 2) + j] = s;
  }
  __syncthreads();
  if (t < PCH) {                               // row p of C only
    const int q = t;
    const float cphi = ctab[p];
    float c0 = 1.f, c1 = cphi;
    float s = 0.5f * G[q * (NQ + 2) + 0];
    for (int j = 1; j <= NQ; ++j) {
      const float w = (j == NQ) ? 0.5f : 1.0f;
      s += w * G[q * (NQ + 2) + j] * c1;
      const float c2 = 2.f * cphi * c1 - c0; c0 = c1; c1 = c2;
    }
    const float cp = (p == 0 ? 1.f : 2.f) / (float)NQ;
    const float cq = (q == 0 ? 1.f : 2.f) / (float)NQ;
    Crow[q] = s * cp * cq;
  }
  // Ms = sum of the 32 private copies (coalesced, L2-resident)
  for (int idx = t; idx < PCH * HID; idx += 256) {
    float s = 0.f;
    #pragma unroll 4
    for (int c = 0; c < NCPY; ++c) s += M32[c * (PCH * HID) + idx];
    Ms[idx] = s;
  }
  __syncthreads();
  if (t < HID) {
    float acc = 0.f;
    #pragma unroll
    for (int q = 0; q < PCH; ++q) acc += Crow[q] * Ms[q * HID + t];
    V[p * HID + t] = acc;
  }
}

// ---- K3: 256 blocks x 512 (4 rows each). Stage V; S = (Cheby - self)/1023;
// out = S @ W2 + b2.
__global__ __launch_bounds__(512) void combine_kernel(
    const float* __restrict__ A, const float* __restrict__ B,
    const float* __restrict__ V, const float* __restrict__ W2,
    const float* __restrict__ b2, float* __restrict__ out) {
  __shared__ float Vl[PCH * HID];        // 15 KB
  __shared__ float Sl[4][HID];
  __shared__ float red[4][2][OUTD];
  const int t = threadIdx.x;
  for (int idx = t; idx < PCH * HID; idx += 512) Vl[idx] = V[idx];
  __syncthreads();
  const int h = t & (HID - 1), row = t >> 7;
  const int i = blockIdx.x * 4 + row;
  const float ar = A[i * HID + h], br = B[i * HID + h];
  const float a = fminf(fmaxf(ar, -S_CH), S_CH) * INV_S;
  float t0 = 1.f, t1 = a;
  const float a2x = a + a;
  float acc = Vl[h] + a * Vl[HID + h];
  #pragma unroll
  for (int p = 2; p < PCH; ++p) {
    const float t2 = a2x * t1 - t0;
    acc += t2 * Vl[p * HID + h];
    t0 = t1; t1 = t2;
  }
  const float ts = tanh_fast(ar + br);   // exact self term (k==i)
  Sl[row][h] = (acc - ts) * (1.f / (float)(N_E - 1));
  __syncthreads();
  const int o = t & (OUTD - 1), half = (t >> 6) & 1, r2 = t >> 7;
  const int h0 = half * 64;
  float po = 0.f;
  #pragma unroll 16
  for (int hh = 0; hh < 64; ++hh)
    po += Sl[r2][h0 + hh] * W2[(h0 + hh) * OUTD + o];   // coalesced over o, L1-hot
  red[r2][half][o] = po;
  __syncthreads();
  if (t < 4 * OUTD) {
    const int rr = t >> 6, oo = t & (OUTD - 1);
    out[(blockIdx.x * 4 + rr) * OUTD + oo] = red[rr][0][oo] + red[rr][1][oo] + b2[oo];
  }
}

extern "C" void kernel_launch(void* const* d_in, const int* in_sizes, int n_in,
                              void* d_out, int out_size, void* d_ws, size_t ws_size,
                              hipStream_t stream) {
  const float* x  = (const float*)d_in[0];
  const float* W1 = (const float*)d_in[1];
  const float* b1 = (const float*)d_in[2];
  const float* W2 = (const float*)d_in[3];
  const float* b2 = (const float*)d_in[4];
  float* out = (float*)d_out;

  float* A   = (float*)d_ws;               // [N_E][HID]
  float* B   = A + N_E * HID;              // [N_E][HID]
  float* M32 = B + N_E * HID;              // [NCPY][PCH][HID]
  float* V   = M32 + NCPY * PCH * HID;     // [PCH][HID]

  prep32_kernel<<<NCPY, 1024, 0, stream>>>(x, W1, b1, A, B, M32);
  v_kernel<<<PCH, 256, 0, stream>>>(M32, V);
  combine_kernel<<<N_E / 4, 512, 0, stream>>>(A, B, V, W2, b2, out);
}